// Round 4
// baseline (180.918 us; speedup 1.0000x reference)
//
#include <hip/hip_runtime.h>
#include <hip/hip_bf16.h>

// INT4 group-quantized decode GEMM (M=64, K=8192, N=28672, GS=128).
// Round 4: barrier-free, LDS-free main kernel.
//  - Each lane buffer_loads exactly its own MFMA B-fragment bytes (SRSRC,
//    uniform soffset = SALU addressing).
//  - Magic dequant: bf16(0x4380|q) = 256+2q exactly; MFMA raw B'=256+2q into
//    per-chunk P; merge y += (s/2)P - s(128+z)*rowsum[m] per group.
//  - rowsum[c][m] = sum of bf16-rounded x over group, from prep pass.
//  - Per-chunk order: A/s/z/rs loads FIRST, sched_barrier, B prefetch LAST
//    -> vmcnt waits never drain the prefetch (fixes R3's drain bug).

typedef float  f32x4 __attribute__((ext_vector_type(4)));
typedef short  s16x8 __attribute__((ext_vector_type(8)));
typedef int    i32x4 __attribute__((ext_vector_type(4)));

#define K_DIM  8192
#define N_DIM  28672
#define BN     64
#define CK     128
#define NCHUNK 64
#define ROWB   (N_DIM * 4)     // byte stride of one qweight row

// A as bf16 cells: [c][k8][m], cell = 8 k-contiguous bf16 of row m.
__device__ s16x8 g_wsa[NCHUNK * 1024];
// rowsum[c][m] = sum over the 128 k of chunk c of bf16-rounded x[m,k] (f32)
__device__ float g_rowsum[NCHUNK * 64];

__device__ int   llvm_amdgcn_raw_buffer_load_i32(i32x4 srsrc, int voff, int soff, int aux) __asm("llvm.amdgcn.raw.buffer.load.i32");
__device__ f32x4 llvm_amdgcn_raw_buffer_load_v4f32(i32x4 srsrc, int voff, int soff, int aux) __asm("llvm.amdgcn.raw.buffer.load.v4f32");

static __device__ __forceinline__ short f2bf(float f) {
    return (short)__builtin_bit_cast(unsigned short, __float2bfloat16(f));
}
static __device__ __forceinline__ float bf2f(short s) {
    return __builtin_bit_cast(float, ((unsigned)(unsigned short)s) << 16);
}
static __device__ __forceinline__ i32x4 make_srsrc(const void* p, unsigned bytes) {
    union { struct { const void* ptr; unsigned rec; unsigned cfg; } s; i32x4 v; } u;
    u.s.ptr = p; u.s.rec = bytes; u.s.cfg = 0x00020000;
    return u.v;
}

__global__ __launch_bounds__(256)
void prep_a_kernel(const float* __restrict__ x) {
    const int tid = threadIdx.x;
    const int c   = blockIdx.x >> 2;        // chunk 0..63
    const int mb  = blockIdx.x & 3;
    const int k8  = tid & 15;               // octet within chunk
    const int m   = mb * 16 + (tid >> 4);
    const float* src = x + (size_t)m * K_DIM + c * CK + k8 * 8;
    f32x4 a = *(const f32x4*)src;
    f32x4 b = *(const f32x4*)(src + 4);
    s16x8 o;
    o[0] = f2bf(a[0]); o[1] = f2bf(a[1]); o[2] = f2bf(a[2]); o[3] = f2bf(a[3]);
    o[4] = f2bf(b[0]); o[5] = f2bf(b[1]); o[6] = f2bf(b[2]); o[7] = f2bf(b[3]);
    g_wsa[(size_t)c * 1024 + k8 * 64 + m] = o;
    // partial sum of the bf16-ROUNDED values (must match what MFMA consumes)
    float ps = 0.f;
#pragma unroll
    for (int j = 0; j < 8; ++j) ps += bf2f(o[j]);
    // reduce over the 16 lanes sharing row m (lane&15 = k8)
    ps += __shfl_xor(ps, 1);
    ps += __shfl_xor(ps, 2);
    ps += __shfl_xor(ps, 4);
    ps += __shfl_xor(ps, 8);
    if (k8 == 0) g_rowsum[c * 64 + m] = ps;
}

__global__ __launch_bounds__(256)
void int4gemm_kernel(const int*   __restrict__ qw,
                     const float* __restrict__ sc,
                     const int*   __restrict__ qz,
                     const float* __restrict__ bias,
                     float*       __restrict__ out)
{
    const int tid   = threadIdx.x;
    const int lane  = tid & 63;
    const int w     = tid >> 6;          // wave 0..3
    const int nbase = blockIdx.x * BN;

    const int l15 = lane & 15;
    const int lk  = lane >> 4;           // k-octet selector 0..3
    const int mh  = w >> 1;              // m-half
    const int nh  = w & 1;               // n-half

    const i32x4 srA = make_srsrc((const void*)g_wsa, NCHUNK * 1024 * 16);
    const i32x4 srB = make_srsrc((const void*)qw, 4096u * (unsigned)ROWB);

    // per-lane constant voffsets
    const int voffA = (lk * 64 + mh * 32 + l15) * 16;                    // bytes
    const int voffB = (lk * 4) * ROWB + (nbase + nh * 32 + l15) * 4;    // bytes
    const int ncol0 = nbase + nh * 32 + l15;

    f32x4 acc[2][2];
#pragma unroll
    for (int mi = 0; mi < 2; ++mi)
#pragma unroll
        for (int ni = 0; ni < 2; ++ni) acc[mi][ni] = (f32x4)0.0f;

    int bvC[32], bvN[32];   // [ (ks*2+nti)*4 + d ]

    // ---- prologue: B bytes for chunk 0 ----
#pragma unroll
    for (int ks = 0; ks < 4; ++ks)
#pragma unroll
        for (int nti = 0; nti < 2; ++nti)
#pragma unroll
            for (int d = 0; d < 4; ++d)
                bvC[(ks * 2 + nti) * 4 + d] =
                    llvm_amdgcn_raw_buffer_load_i32(srB, voffB + nti * 64,
                                                    (ks * 16 + d) * ROWB, 0);

#pragma unroll 2
    for (int c = 0; c < NCHUNK; ++c) {
        // ---- (1) A fragments + s/z/rowsum for THIS chunk (issued first) ----
        f32x4 af[8];
#pragma unroll
        for (int ks = 0; ks < 4; ++ks)
#pragma unroll
            for (int mi = 0; mi < 2; ++mi)
                af[ks * 2 + mi] = llvm_amdgcn_raw_buffer_load_v4f32(
                    srA, voffA + mi * 256, c * 16384 + ks * 4096, 0);
        const float s0 = sc[(size_t)c * N_DIM + ncol0];
        const float s1 = sc[(size_t)c * N_DIM + ncol0 + 16];
        const int   z0 = qz[(size_t)c * N_DIM + ncol0];
        const int   z1 = qz[(size_t)c * N_DIM + ncol0 + 16];
        const f32x4 rs0 = *(const f32x4*)&g_rowsum[c * 64 + mh * 32 + lk * 4];
        const f32x4 rs1 = *(const f32x4*)&g_rowsum[c * 64 + mh * 32 + 16 + lk * 4];

        // pin: nothing below may be hoisted above (keeps A older than B-prefetch)
        __builtin_amdgcn_sched_barrier(0);

        // ---- (2) B prefetch for NEXT chunk (issued last; stays in flight) ----
        const int cb = (c + 1) & (NCHUNK - 1);
#pragma unroll
        for (int ks = 0; ks < 4; ++ks)
#pragma unroll
            for (int nti = 0; nti < 2; ++nti)
#pragma unroll
                for (int d = 0; d < 4; ++d)
                    bvN[(ks * 2 + nti) * 4 + d] =
                        llvm_amdgcn_raw_buffer_load_i32(srB, voffB + nti * 64,
                                                        (cb * 64 + ks * 16 + d) * ROWB, 0);

        // ---- (3) magic-convert current B bytes: B' = 256 + 2q (exact bf16) ----
        s16x8 bf[8];
#pragma unroll
        for (int fi = 0; fi < 8; ++fi) {
            i32x4 f;
#pragma unroll
            for (int d = 0; d < 4; ++d) {
                const int v = bvC[fi * 4 + d];
                f[d] = 0x43804380 | (v & 15) | ((v >> 4) << 16);
            }
            bf[fi] = __builtin_bit_cast(s16x8, f);
        }

        // ---- (4) MFMA into fresh per-chunk accumulator P ----
        f32x4 pc[2][2];
#pragma unroll
        for (int mi = 0; mi < 2; ++mi)
#pragma unroll
            for (int ni = 0; ni < 2; ++ni) pc[mi][ni] = (f32x4)0.0f;
#pragma unroll
        for (int ks = 0; ks < 4; ++ks) {
#pragma unroll
            for (int mi = 0; mi < 2; ++mi) {
                const s16x8 a = __builtin_bit_cast(s16x8, af[ks * 2 + mi]);
                pc[mi][0] = __builtin_amdgcn_mfma_f32_16x16x32_bf16(a, bf[ks * 2 + 0], pc[mi][0], 0, 0, 0);
                pc[mi][1] = __builtin_amdgcn_mfma_f32_16x16x32_bf16(a, bf[ks * 2 + 1], pc[mi][1], 0, 0, 0);
            }
        }

        // ---- (5) merge: y += (s/2)P - s(128+z)*rowsum ----
        const float h0 = 0.5f * s0, w0 = s0 * (128.0f + (float)z0);
        const float h1 = 0.5f * s1, w1 = s1 * (128.0f + (float)z1);
#pragma unroll
        for (int mi = 0; mi < 2; ++mi) {
            const f32x4 rs = mi ? rs1 : rs0;
#pragma unroll
            for (int j = 0; j < 4; ++j) {
                acc[mi][0][j] = fmaf(pc[mi][0][j], h0, fmaf(rs[j], -w0, acc[mi][0][j]));
                acc[mi][1][j] = fmaf(pc[mi][1][j], h1, fmaf(rs[j], -w1, acc[mi][1][j]));
            }
        }

        // ---- (6) rotate (copy-propagated by the x2 unroll) ----
#pragma unroll
        for (int u = 0; u < 32; ++u) bvC[u] = bvN[u];
    }

    // ---- epilogue: bias + store ----
#pragma unroll
    for (int nti = 0; nti < 2; ++nti) {
        const int   ncol = ncol0 + nti * 16;
        const float bv   = bias[ncol];
#pragma unroll
        for (int mi = 0; mi < 2; ++mi) {
#pragma unroll
            for (int j = 0; j < 4; ++j) {
                const int m = mh * 32 + mi * 16 + lk * 4 + j;
                out[(size_t)m * N_DIM + ncol] = acc[mi][nti][j] + bv;
            }
        }
    }
}

extern "C" void kernel_launch(void* const* d_in, const int* in_sizes, int n_in,
                              void* d_out, int out_size, void* d_ws, size_t ws_size,
                              hipStream_t stream) {
    const float* x    = (const float*)d_in[0];
    const int*   qw   = (const int*)d_in[1];
    const float* sc   = (const float*)d_in[2];
    const int*   qz   = (const int*)d_in[3];
    const float* bias = (const float*)d_in[4];
    float*       out  = (float*)d_out;

    prep_a_kernel<<<dim3(256), dim3(256), 0, stream>>>(x);
    int4gemm_kernel<<<dim3(N_DIM / BN), dim3(256), 0, stream>>>(qw, sc, qz, bias, out);
}

// Round 5
// 146.670 us; speedup vs baseline: 1.2335x; 1.2335x over previous
//
#include <hip/hip_runtime.h>
#include <hip/hip_bf16.h>

// INT4 group-quantized decode GEMM (M=64, K=8192, N=28672, GS=128).
// Round 5: R2 skeleton + A-fragments direct from L2 (no lA), double-buffered
// lB with ONE barrier/chunk, conflict-free B staging, issue-order-pinned
// prefetch (A first, B(c+2) last) so no wait ever drains the pipeline.

typedef float  f32x4 __attribute__((ext_vector_type(4)));
typedef short  s16x8 __attribute__((ext_vector_type(8)));
typedef int    i32x4 __attribute__((ext_vector_type(4)));

#define K_DIM  8192
#define N_DIM  28672
#define BN     64
#define CK     128
#define NCHUNK 64            // K / CK; chunk == scale group

// A as bf16 cells: [c][k8][m], cell = 8 k-contiguous bf16 of row m.
__device__ s16x8 g_wsa[NCHUNK * 1024];

__device__ f32x4 llvm_amdgcn_raw_buffer_load_v4f32(i32x4 srsrc, int voff, int soff, int aux) __asm("llvm.amdgcn.raw.buffer.load.v4f32");

static __device__ __forceinline__ short f2bf(float f) {
    return (short)__builtin_bit_cast(unsigned short, __float2bfloat16(f));
}
static __device__ __forceinline__ i32x4 make_srsrc(const void* p, unsigned bytes) {
    union { struct { const void* ptr; unsigned rec; unsigned cfg; } s; i32x4 v; } u;
    u.s.ptr = p; u.s.rec = bytes; u.s.cfg = 0x00020000;
    return u.v;
}

__global__ __launch_bounds__(256)
void prep_a_kernel(const float* __restrict__ x) {
    const int tid = threadIdx.x;
    const int c   = blockIdx.x >> 2;        // chunk 0..63
    const int mb  = blockIdx.x & 3;
    const int k8  = tid & 15;
    const int m   = mb * 16 + (tid >> 4);
    const float* src = x + (size_t)m * K_DIM + c * CK + k8 * 8;
    f32x4 a = *(const f32x4*)src;
    f32x4 b = *(const f32x4*)(src + 4);
    s16x8 o;
    o[0] = f2bf(a[0]); o[1] = f2bf(a[1]); o[2] = f2bf(a[2]); o[3] = f2bf(a[3]);
    o[4] = f2bf(b[0]); o[5] = f2bf(b[1]); o[6] = f2bf(b[2]); o[7] = f2bf(b[3]);
    g_wsa[(size_t)c * 1024 + k8 * 64 + m] = o;
}

__global__ __launch_bounds__(512, 4)
void int4gemm_kernel(const int*   __restrict__ qw,
                     const float* __restrict__ sc,
                     const int*   __restrict__ qz,
                     const float* __restrict__ bias,
                     float*       __restrict__ out)
{
    // B cells, double-buffered: [buf][k8 0..15][col 0..63]
    __shared__ s16x8 lB[2][16 * 64];

    const int tid   = threadIdx.x;
    const int lane  = tid & 63;
    const int w     = tid >> 6;          // wave 0..7
    const int nbase = blockIdx.x * BN;

    // ---- B staging: thread owns ONE col (= lane), 8 byte-rows (8w..8w+7) ----
    // Loads: lanes 0..63 consecutive cols, same row -> 256B/instr coalesced.
    // Writes: wave w writes cells (2w)*64+lane, (2w+1)*64+lane -> lane-linear
    //         1KB ds_write_b128, conflict-free.
    const int col  = lane;
    const int*   qcol = qw + nbase + col;
    const float* scol = sc + nbase + col;
    const int*   zcol = qz + nbase + col;

    // ---- MFMA coords (R2-validated): 8 waves = 2 m-halves x 4 n-tiles ----
    const int l15 = lane & 15;
    const int lk  = lane >> 4;
    const int mh  = w >> 2;
    const int wn  = (w & 3) * 16;

    const i32x4 srA  = make_srsrc((const void*)g_wsa, NCHUNK * 1024 * 16);
    const int   voffA = (lk * 64 + mh * 32 + l15) * 16;   // + mi*256 bytes

    f32x4 acc[2];
    acc[0] = (f32x4)0.0f;
    acc[1] = (f32x4)0.0f;

    // ---- pipeline registers (2-deep for B and s/z) ----
    int   bvC[8], bvB[8], bvN[8];
    float sC, sB_, sN_;
    int   zC, zB_, zN_;

    // prologue: B chunks 0,1; s/z groups 0,1
#pragma unroll
    for (int u = 0; u < 8; ++u) {
        bvC[u] = qcol[(size_t)(8 * w + u) * N_DIM];
        bvB[u] = qcol[(size_t)(64 + 8 * w + u) * N_DIM];
    }
    sC  = scol[0];               zC  = zcol[0];
    sB_ = scol[N_DIM];           zB_ = zcol[N_DIM];

#pragma unroll 2
    for (int c = 0; c < NCHUNK; ++c) {
        // ---- (1) A fragments for THIS chunk, issued FIRST (oldest) ----
        f32x4 af[8];
#pragma unroll
        for (int ks = 0; ks < 4; ++ks)
#pragma unroll
            for (int mi = 0; mi < 2; ++mi)
                af[ks * 2 + mi] = llvm_amdgcn_raw_buffer_load_v4f32(
                    srA, voffA + mi * 256, c * 16384 + ks * 4096, 0);
        __builtin_amdgcn_sched_barrier(0);

        // ---- (2) B + s/z prefetch for chunk c+2, issued LAST (youngest) ----
        const int cb = (c + 2) & (NCHUNK - 1);   // wrap: harmless reload
#pragma unroll
        for (int u = 0; u < 8; ++u)
            bvN[u] = qcol[(size_t)(cb * 64 + 8 * w + u) * N_DIM];
        sN_ = scol[(size_t)cb * N_DIM];
        zN_ = zcol[(size_t)cb * N_DIM];
        __builtin_amdgcn_sched_barrier(0);

        // ---- (3) dequant current B bytes (loaded 2 iters ago) -> 2 cells ----
        const float s = sC;
        const float o = -(float)zC * s;
        s16x8 c0, c1;
#pragma unroll
        for (int uu = 0; uu < 4; ++uu) {
            const int v0 = bvC[uu];
            const int v1 = bvC[4 + uu];
            c0[2 * uu]     = f2bf(fmaf((float)(v0 & 15), s, o));
            c0[2 * uu + 1] = f2bf(fmaf((float)(v0 >> 4), s, o));
            c1[2 * uu]     = f2bf(fmaf((float)(v1 & 15), s, o));
            c1[2 * uu + 1] = f2bf(fmaf((float)(v1 >> 4), s, o));
        }
        lB[c & 1][(2 * w) * 64 + col]     = c0;
        lB[c & 1][(2 * w + 1) * 64 + col] = c1;

        // ---- (4) single barrier: writes of buf[c&1] visible ----
        asm volatile("s_waitcnt lgkmcnt(0)" ::: "memory");
        asm volatile("s_barrier" ::: "memory");

        // ---- (5) MFMA: 4 ksteps x 2 m-tiles x 1 n-tile ----
#pragma unroll
        for (int ks = 0; ks < 4; ++ks) {
            const s16x8 bfr = lB[c & 1][(ks * 4 + lk) * 64 + wn + l15];
            const s16x8 a0  = __builtin_bit_cast(s16x8, af[ks * 2 + 0]);
            const s16x8 a1  = __builtin_bit_cast(s16x8, af[ks * 2 + 1]);
            acc[0] = __builtin_amdgcn_mfma_f32_16x16x32_bf16(a0, bfr, acc[0], 0, 0, 0);
            acc[1] = __builtin_amdgcn_mfma_f32_16x16x32_bf16(a1, bfr, acc[1], 0, 0, 0);
        }

        // ---- (6) rotate pipeline ----
#pragma unroll
        for (int u = 0; u < 8; ++u) { bvC[u] = bvB[u]; bvB[u] = bvN[u]; }
        sC = sB_; sB_ = sN_;
        zC = zB_; zB_ = zN_;
    }

    // ---- epilogue: bias + store (verified C layout) ----
    const int   ncol = nbase + wn + l15;
    const float bv   = bias[ncol];
#pragma unroll
    for (int mi = 0; mi < 2; ++mi) {
#pragma unroll
        for (int j = 0; j < 4; ++j) {
            const int m = mh * 32 + mi * 16 + lk * 4 + j;
            out[(size_t)m * N_DIM + ncol] = acc[mi][j] + bv;
        }
    }
}

extern "C" void kernel_launch(void* const* d_in, const int* in_sizes, int n_in,
                              void* d_out, int out_size, void* d_ws, size_t ws_size,
                              hipStream_t stream) {
    const float* x    = (const float*)d_in[0];
    const int*   qw   = (const int*)d_in[1];
    const float* sc   = (const float*)d_in[2];
    const int*   qz   = (const int*)d_in[3];
    const float* bias = (const float*)d_in[4];
    float*       out  = (float*)d_out;

    prep_a_kernel<<<dim3(256), dim3(256), 0, stream>>>(x);
    int4gemm_kernel<<<dim3(N_DIM / BN), dim3(512), 0, stream>>>(qw, sc, qz, bias, out);
}

// Round 6
// 132.234 us; speedup vs baseline: 1.3682x; 1.1092x over previous
//
#include <hip/hip_runtime.h>
#include <hip/hip_bf16.h>

// INT4 group-quantized decode GEMM (M=64, K=8192, N=28672, GS=128).
// Round 6: R2 champion inner loop, UNCHANGED + K-split x4 for exact CU
// balance (1792 blocks = 7.0/CU vs 448 = 1.75/CU). Partials merged with
// f32 atomics into a memset-zeroed d_out; bias added by ksplit-0 blocks.

typedef float  f32x4 __attribute__((ext_vector_type(4)));
typedef float  f32x2 __attribute__((ext_vector_type(2)));
typedef short  s16x8 __attribute__((ext_vector_type(8)));
typedef int    i32x2 __attribute__((ext_vector_type(2)));
typedef int    i32x4 __attribute__((ext_vector_type(4)));

#define M_DIM 64
#define K_DIM 8192
#define N_DIM 28672
#define BN    64             // output cols per block
#define CK    128            // k per chunk == group_size
#define NCHUNK 64            // total chunks
#define KSPLIT 4
#define NCH_L  (NCHUNK / KSPLIT)   // 16 chunks per block
#define NB     (N_DIM / BN)        // 448 n-blocks

// A in bf16 cell layout: cell (c, k8, m) = 8 k-contiguous bf16 of row m.
__device__ s16x8 g_wsa[NCHUNK * 1024];

static __device__ __forceinline__ short f2bf(float f) {
    return (short)__builtin_bit_cast(unsigned short, __float2bfloat16(f));
}

__global__ __launch_bounds__(256)
void prep_a_kernel(const float* __restrict__ x) {
    const int tid = threadIdx.x;
    const int c   = blockIdx.x >> 2;        // 0..63
    const int mb  = blockIdx.x & 3;
    const int k8  = tid & 15;
    const int m   = mb * 16 + (tid >> 4);
    const float* src = x + (size_t)m * K_DIM + c * CK + k8 * 8;
    f32x4 a = *(const f32x4*)src;
    f32x4 b = *(const f32x4*)(src + 4);
    s16x8 o;
    o[0] = f2bf(a[0]); o[1] = f2bf(a[1]); o[2] = f2bf(a[2]); o[3] = f2bf(a[3]);
    o[4] = f2bf(b[0]); o[5] = f2bf(b[1]); o[6] = f2bf(b[2]); o[7] = f2bf(b[3]);
    g_wsa[(size_t)c * 1024 + k8 * 64 + m] = o;
}

__global__ __launch_bounds__(512, 4)
void int4gemm_kernel(const int*   __restrict__ qw,
                     const float* __restrict__ sc,
                     const int*   __restrict__ qz,
                     const float* __restrict__ bias,
                     float*       __restrict__ out)
{
    // 16B cells: [k8 0..15][idx 0..63]
    __shared__ s16x8 lB[16 * 64];   // idx = col within block
    __shared__ s16x8 lA[16 * 64];   // idx = batch row m

    const int tid   = threadIdx.x;
    const int lane  = tid & 63;
    const int wave  = tid >> 6;      // 0..7
    const int nb    = blockIdx.x % NB;
    const int ksp   = blockIdx.x / NB;       // 0..3
    const int kbase = ksp * NCH_L;           // first chunk of this split
    const int nbase = nb * BN;

    // B staging: thread owns cols (2p, 2p+1) x byte-rows q*4..q*4+3 (cell k8=q)
    const int p  = tid & 31;
    const int q  = tid >> 5;         // 0..15
    const int j0 = nbase + 2 * p;

    // MFMA coords: 8 waves = 2 (m-half) x 4 (n-tile)
    const int l15 = lane & 15;
    const int lk  = lane >> 4;       // 0..3
    const int mh  = wave >> 2;       // 0..1
    const int wn  = (wave & 3) * 16; // n-tile base

    f32x4 acc0 = (f32x4)0.0f, acc1 = (f32x4)0.0f;

    const int* qbase = qw + j0;
    const i32x4* wsa4 = (const i32x4*)g_wsa;

    // ---- pipeline registers ----
    i32x2 bvA[4], bvB[4], bvN[4];    // qweight: cur / +1 / +2
    i32x4 av0, av1;                  // A cells for next chunk to stage
    f32x2 sA, sB, sN;
    i32x2 zA, zB, zN;

    // prologue: B chunks kbase, kbase+1; scales same; A chunk kbase
#pragma unroll
    for (int r = 0; r < 4; ++r) {
        bvA[r] = *(const i32x2*)(qbase + (size_t)((kbase)     * 64 + q * 4 + r) * N_DIM);
        bvB[r] = *(const i32x2*)(qbase + (size_t)((kbase + 1) * 64 + q * 4 + r) * N_DIM);
    }
    sA = *(const f32x2*)(sc + (size_t)kbase * N_DIM + j0);
    sB = *(const f32x2*)(sc + (size_t)(kbase + 1) * N_DIM + j0);
    zA = *(const i32x2*)(qz + (size_t)kbase * N_DIM + j0);
    zB = *(const i32x2*)(qz + (size_t)(kbase + 1) * N_DIM + j0);
    av0 = wsa4[(size_t)kbase * 1024 + tid];
    av1 = wsa4[(size_t)kbase * 1024 + 512 + tid];

#pragma unroll 2
    for (int c = 0; c < NCH_L; ++c) {
        // ---- dequant current qweight quad (regs loaded 2 iters ago) ----
        const float s0 = sA.x, s1 = sA.y;
        const float o0 = -(float)zA.x * s0;
        const float o1 = -(float)zA.y * s1;
        s16x8 c0, c1;
#pragma unroll
        for (int r = 0; r < 4; ++r) {
            const int vx = bvA[r].x, vy = bvA[r].y;
            c0[2 * r]     = f2bf(fmaf((float)(vx & 15),        s0, o0));
            c0[2 * r + 1] = f2bf(fmaf((float)((vx >> 4) & 15), s0, o0));
            c1[2 * r]     = f2bf(fmaf((float)(vy & 15),        s1, o1));
            c1[2 * r + 1] = f2bf(fmaf((float)((vy >> 4) & 15), s1, o1));
        }

        // barrier1: previous MFMA phase done reading LDS (no vmem drain)
        asm volatile("s_barrier" ::: "memory");

        // stage this chunk's tiles
        lB[q * 64 + 2 * p]          = c0;
        lB[q * 64 + 2 * p + 1]      = c1;
        lA[tid]       = __builtin_bit_cast(s16x8, av0);
        lA[512 + tid] = __builtin_bit_cast(s16x8, av1);

        // prefetch: A for c+1, B + scales for c+2 (clamped at tail:
        // re-reads an L2-hot chunk instead of fetching discarded data)
        const int ca = kbase + ((c + 1 < NCH_L) ? c + 1 : NCH_L - 1);
        av0 = wsa4[(size_t)ca * 1024 + tid];
        av1 = wsa4[(size_t)ca * 1024 + 512 + tid];
        const int cb = kbase + ((c + 2 < NCH_L) ? c + 2 : NCH_L - 1);
#pragma unroll
        for (int r = 0; r < 4; ++r)
            bvN[r] = *(const i32x2*)(qbase + (size_t)(cb * 64 + q * 4 + r) * N_DIM);
        sN = *(const f32x2*)(sc + (size_t)cb * N_DIM + j0);
        zN = *(const i32x2*)(qz + (size_t)cb * N_DIM + j0);

        // barrier2: LDS writes visible; vmem prefetches stay in flight
        asm volatile("s_waitcnt lgkmcnt(0)" ::: "memory");
        asm volatile("s_barrier" ::: "memory");
        __builtin_amdgcn_sched_barrier(0);

        // ---- MFMA: wave does 2 m-tiles x 1 n-tile x 4 k-slices ----
#pragma unroll
        for (int ks = 0; ks < 4; ++ks) {
            const int cell = (ks * 4 + lk) * 64;
            const s16x8 bfr = lB[cell + wn + l15];
            const s16x8 af0 = lA[cell + mh * 32 + l15];
            const s16x8 af1 = lA[cell + mh * 32 + 16 + l15];
            acc0 = __builtin_amdgcn_mfma_f32_16x16x32_bf16(af0, bfr, acc0, 0, 0, 0);
            acc1 = __builtin_amdgcn_mfma_f32_16x16x32_bf16(af1, bfr, acc1, 0, 0, 0);
        }

        // rotate pipeline
#pragma unroll
        for (int r = 0; r < 4; ++r) { bvA[r] = bvB[r]; bvB[r] = bvN[r]; }
        sA = sB; sB = sN; zA = zB; zB = zN;
    }

    // ---- epilogue: atomic-merge partials (+bias once, from ksplit 0) ----
    const int   ncol = nbase + wn + l15;
    const float bv   = (ksp == 0) ? bias[ncol] : 0.0f;
    const int   m0   = mh * 32 + lk * 4;
#pragma unroll
    for (int jj = 0; jj < 4; ++jj) {
        atomicAdd(&out[(size_t)(m0 + jj) * N_DIM + ncol],      acc0[jj] + bv);
        atomicAdd(&out[(size_t)(m0 + 16 + jj) * N_DIM + ncol], acc1[jj] + bv);
    }
}

extern "C" void kernel_launch(void* const* d_in, const int* in_sizes, int n_in,
                              void* d_out, int out_size, void* d_ws, size_t ws_size,
                              hipStream_t stream) {
    const float* x    = (const float*)d_in[0];
    const int*   qw   = (const int*)d_in[1];
    const float* sc   = (const float*)d_in[2];
    const int*   qz   = (const int*)d_in[3];
    const float* bias = (const float*)d_in[4];
    float*       out  = (float*)d_out;

    // zero the accumulation target each call (atomics make this mandatory;
    // memset node is graph-capture-safe — the harness itself uses them)
    hipMemsetAsync(d_out, 0, (size_t)out_size * sizeof(float), stream);
    prep_a_kernel<<<dim3(256), dim3(256), 0, stream>>>(x);
    int4gemm_kernel<<<dim3(NB * KSPLIT), dim3(512), 0, stream>>>(qw, sc, qz, bias, out);
}

// Round 7
// 129.931 us; speedup vs baseline: 1.3924x; 1.0177x over previous
//
#include <hip/hip_runtime.h>
#include <hip/hip_bf16.h>

// INT4 group-quantized decode GEMM (M=64, K=8192, N=28672, GS=128).
// Round 7: 32x32x16 bf16 MFMA (2x LDS reuse), A-fragments direct from
// L2-resident g_wsa via 1KB coalesced buffer loads, B-only LDS double-buffer
// with ONE barrier per chunk, strict issue-order (A first, B-prefetch last).

typedef float  f32x2  __attribute__((ext_vector_type(2)));
typedef float  f32x4  __attribute__((ext_vector_type(4)));
typedef float  f32x16 __attribute__((ext_vector_type(16)));
typedef short  s16x8  __attribute__((ext_vector_type(8)));
typedef int    i32x2  __attribute__((ext_vector_type(2)));
typedef int    i32x4  __attribute__((ext_vector_type(4)));

#define K_DIM  8192
#define N_DIM  28672
#define BN     64
#define CK     128
#define NCHUNK 64            // K / CK; chunk == scale group
#define NB     (N_DIM / BN)  // 448 blocks

// A as bf16 cells: [c][k8][m], cell = 8 k-contiguous bf16 of row m.
__device__ s16x8 g_wsa[NCHUNK * 1024];

__device__ f32x4 llvm_amdgcn_raw_buffer_load_v4f32(i32x4 srsrc, int voff, int soff, int aux) __asm("llvm.amdgcn.raw.buffer.load.v4f32");

static __device__ __forceinline__ short f2bf(float f) {
    return (short)__builtin_bit_cast(unsigned short, __float2bfloat16(f));
}
static __device__ __forceinline__ i32x4 make_srsrc(const void* p, unsigned bytes) {
    union { struct { const void* ptr; unsigned rec; unsigned cfg; } s; i32x4 v; } u;
    u.s.ptr = p; u.s.rec = bytes; u.s.cfg = 0x00020000;
    return u.v;
}

__global__ __launch_bounds__(256)
void prep_a_kernel(const float* __restrict__ x) {
    const int tid = threadIdx.x;
    const int c   = blockIdx.x >> 2;        // chunk 0..63
    const int mb  = blockIdx.x & 3;
    const int k8  = tid & 15;
    const int m   = mb * 16 + (tid >> 4);
    const float* src = x + (size_t)m * K_DIM + c * CK + k8 * 8;
    f32x4 a = *(const f32x4*)src;
    f32x4 b = *(const f32x4*)(src + 4);
    s16x8 o;
    o[0] = f2bf(a[0]); o[1] = f2bf(a[1]); o[2] = f2bf(a[2]); o[3] = f2bf(a[3]);
    o[4] = f2bf(b[0]); o[5] = f2bf(b[1]); o[6] = f2bf(b[2]); o[7] = f2bf(b[3]);
    g_wsa[(size_t)c * 1024 + k8 * 64 + m] = o;
}

__global__ __launch_bounds__(256, 3)
void int4gemm_kernel(const int*   __restrict__ qw,
                     const float* __restrict__ sc,
                     const int*   __restrict__ qz,
                     const float* __restrict__ bias,
                     float*       __restrict__ out)
{
    // B cells, double-buffered: [buf][k8 0..15][col 0..63]
    __shared__ s16x8 lB[2][16 * 64];

    const int tid   = threadIdx.x;
    const int lane  = tid & 63;
    const int w     = tid >> 6;          // wave 0..3
    const int nbase = blockIdx.x * BN;

    // ---- B staging: thread owns col-pair (2p,2p+1) x octets {q, q+8} ----
    const int p  = tid & 31;
    const int q  = tid >> 5;             // 0..7
    const int j0 = nbase + 2 * p;

    // ---- MFMA coords: wave = one 32x32 tile; (tm, tn) in 2x2 ----
    const int l31 = lane & 31;
    const int lh  = lane >> 5;           // k-half selector
    const int tm  = w >> 1;
    const int tn  = w & 1;

    const i32x4 srA   = make_srsrc((const void*)g_wsa, NCHUNK * 1024 * 16);
    const int   voffA = lh * 1024 + (tm * 32 + l31) * 16;   // lane part, bytes

    const int*   qbase = qw + j0;
    const float* scp   = sc + j0;
    const int*   qzp   = qz + j0;

    f32x16 acc = (f32x16)0.0f;

    i32x2 bvC[8], bvN[8];   // [o2*4 + r]: octet q+8*o2, byte-row r
    f32x2 sC, sN;
    i32x2 zC, zN;

    // ---- prologue: B/s/z for chunk 0 ----
#pragma unroll
    for (int o2 = 0; o2 < 2; ++o2)
#pragma unroll
        for (int r = 0; r < 4; ++r)
            bvC[o2 * 4 + r] = *(const i32x2*)(qbase + (size_t)((q + 8 * o2) * 4 + r) * N_DIM);
    sC = *(const f32x2*)scp;
    zC = *(const i32x2*)qzp;

#pragma unroll 2
    for (int c = 0; c < NCHUNK; ++c) {
        // ---- (1) A-fragments for THIS chunk, issued FIRST (oldest) ----
        f32x4 af[8];
#pragma unroll
        for (int ks = 0; ks < 8; ++ks)
            af[ks] = llvm_amdgcn_raw_buffer_load_v4f32(srA, voffA,
                                                       c * 16384 + ks * 2048, 0);
        __builtin_amdgcn_sched_barrier(0);

        // ---- (2) B/s/z prefetch for chunk c+1, issued LAST (youngest) ----
        const int cn = (c + 1) & (NCHUNK - 1);   // wrap: harmless L2-hot reload
#pragma unroll
        for (int o2 = 0; o2 < 2; ++o2)
#pragma unroll
            for (int r = 0; r < 4; ++r)
                bvN[o2 * 4 + r] = *(const i32x2*)(qbase +
                    (size_t)(cn * 64 + (q + 8 * o2) * 4 + r) * N_DIM);
        sN = *(const f32x2*)(scp + (size_t)cn * N_DIM);
        zN = *(const i32x2*)(qzp + (size_t)cn * N_DIM);
        __builtin_amdgcn_sched_barrier(0);

        // ---- (3) dequant current B (chunk-old regs; wait leaves 1&2 in flight) ----
        const float s0 = sC.x, s1 = sC.y;
        const float o0 = -(float)zC.x * s0;
        const float o1 = -(float)zC.y * s1;
#pragma unroll
        for (int o2 = 0; o2 < 2; ++o2) {
            s16x8 c0, c1;
#pragma unroll
            for (int r = 0; r < 4; ++r) {
                const int vx = bvC[o2 * 4 + r].x;
                const int vy = bvC[o2 * 4 + r].y;
                c0[2 * r]     = f2bf(fmaf((float)(vx & 15), s0, o0));
                c0[2 * r + 1] = f2bf(fmaf((float)(vx >> 4), s0, o0));
                c1[2 * r]     = f2bf(fmaf((float)(vy & 15), s1, o1));
                c1[2 * r + 1] = f2bf(fmaf((float)(vy >> 4), s1, o1));
            }
            lB[c & 1][(q + 8 * o2) * 64 + 2 * p]     = c0;
            lB[c & 1][(q + 8 * o2) * 64 + 2 * p + 1] = c1;
        }

        // ---- (4) ONE barrier: buf[c&1] writes visible; prefetches in flight ----
        asm volatile("s_waitcnt lgkmcnt(0)" ::: "memory");
        __builtin_amdgcn_s_barrier();

        // ---- (5) MFMA: 8 k-steps, one 32x32 tile per wave ----
#pragma unroll
        for (int ks = 0; ks < 8; ++ks) {
            const s16x8 bfr = lB[c & 1][(2 * ks + lh) * 64 + tn * 32 + l31];
            const s16x8 a   = __builtin_bit_cast(s16x8, af[ks]);
            acc = __builtin_amdgcn_mfma_f32_32x32x16_bf16(a, bfr, acc, 0, 0, 0);
        }

        // ---- (6) rotate pipeline ----
#pragma unroll
        for (int u = 0; u < 8; ++u) bvC[u] = bvN[u];
        sC = sN;
        zC = zN;
    }

    // ---- epilogue: bias + store (m74/m101-verified 32x32 C/D layout) ----
    const int   ncol = nbase + tn * 32 + l31;
    const float bv   = bias[ncol];
#pragma unroll
    for (int reg = 0; reg < 16; ++reg) {
        const int m = tm * 32 + (reg & 3) + 8 * (reg >> 2) + 4 * lh;
        out[(size_t)m * N_DIM + ncol] = acc[reg] + bv;
    }
}

extern "C" void kernel_launch(void* const* d_in, const int* in_sizes, int n_in,
                              void* d_out, int out_size, void* d_ws, size_t ws_size,
                              hipStream_t stream) {
    const float* x    = (const float*)d_in[0];
    const int*   qw   = (const int*)d_in[1];
    const float* sc   = (const float*)d_in[2];
    const int*   qz   = (const int*)d_in[3];
    const float* bias = (const float*)d_in[4];
    float*       out  = (float*)d_out;

    prep_a_kernel<<<dim3(256), dim3(256), 0, stream>>>(x);
    int4gemm_kernel<<<dim3(NB), dim3(256), 0, stream>>>(qw, sc, qz, bias, out);
}

// Round 8
// 123.457 us; speedup vs baseline: 1.4654x; 1.0524x over previous
//
#include <hip/hip_runtime.h>
#include <hip/hip_bf16.h>
#include <hip/hip_fp16.h>

// INT4 group-quantized decode GEMM (M=64, K=8192, N=28672, GS=128).
// Round 8: R2 champion skeleton (512 thr, lA+lB single-buffer, two raw
// s_barriers, 2-deep B prefetch, 1-deep A prefetch) with ONE change:
// dequant via packed-f16 magic (0x6400|q = 1024+q exact; pk_add exact q-z;
// pk_mul single-rounded s*(q-z)) and f16 MFMA. ~2.5x fewer dequant VALU ops
// and better precision (2^-11 vs 2^-8).

typedef float  f32x4 __attribute__((ext_vector_type(4)));
typedef float  f32x2 __attribute__((ext_vector_type(2)));
typedef short  s16x8 __attribute__((ext_vector_type(8)));
typedef _Float16 f16x8 __attribute__((ext_vector_type(8)));
typedef int    i32x2 __attribute__((ext_vector_type(2)));
typedef int    i32x4 __attribute__((ext_vector_type(4)));

#define M_DIM 64
#define K_DIM 8192
#define N_DIM 28672
#define BN    64             // output cols per block
#define CK    128            // k per chunk == group_size
#define NCHUNK (K_DIM / CK)  // 64

// A in f16 cell layout: cell (c, k8, m) = 8 k-contiguous f16 of row m.
__device__ s16x8 g_wsa[NCHUNK * 1024];

static __device__ __forceinline__ short f2h(float f) {
    return (short)__builtin_bit_cast(unsigned short, __float2half(f));
}

__global__ __launch_bounds__(256)
void prep_a_kernel(const float* __restrict__ x) {
    const int tid = threadIdx.x;
    const int c   = blockIdx.x >> 2;        // 0..63
    const int mb  = blockIdx.x & 3;
    const int k8  = tid & 15;
    const int m   = mb * 16 + (tid >> 4);
    const float* src = x + (size_t)m * K_DIM + c * CK + k8 * 8;
    f32x4 a = *(const f32x4*)src;
    f32x4 b = *(const f32x4*)(src + 4);
    s16x8 o;
    o[0] = f2h(a[0]); o[1] = f2h(a[1]); o[2] = f2h(a[2]); o[3] = f2h(a[3]);
    o[4] = f2h(b[0]); o[5] = f2h(b[1]); o[6] = f2h(b[2]); o[7] = f2h(b[3]);
    g_wsa[(size_t)c * 1024 + k8 * 64 + m] = o;
}

// dequant one qweight byte-pair column word: v in [0,255] ->
// two f16 weights (k-even, k-odd) = s * (q - z), exactly-cancelled via f16.
static __device__ __forceinline__ unsigned dq_word(int v, __half2 cz, __half2 cs) {
    const unsigned t = ((unsigned)(v & 15) | ((unsigned)(v & 0xF0) << 12)) | 0x64006400u;
    const __half2 h = __builtin_bit_cast(__half2, t);       // (1024+lo, 1024+hi)
    const __half2 w = __hmul2(__hadd2(h, cz), cs);          // exact (q-z) * s
    return __builtin_bit_cast(unsigned, w);
}

__global__ __launch_bounds__(512, 4)
void int4gemm_kernel(const int*   __restrict__ qw,
                     const float* __restrict__ sc,
                     const int*   __restrict__ qz,
                     const float* __restrict__ bias,
                     float*       __restrict__ out)
{
    // 16B cells: [k8 0..15][idx 0..63]
    __shared__ s16x8 lB[16 * 64];   // idx = col within block
    __shared__ s16x8 lA[16 * 64];   // idx = batch row m

    const int tid   = threadIdx.x;
    const int lane  = tid & 63;
    const int wave  = tid >> 6;      // 0..7
    const int nbase = blockIdx.x * BN;

    // B staging: thread owns cols (2p, 2p+1) x byte-rows q*4..q*4+3 (cell k8=q)
    const int p  = tid & 31;
    const int q  = tid >> 5;         // 0..15
    const int j0 = nbase + 2 * p;

    // MFMA coords: 8 waves = 2 (m-half) x 4 (n-tile)
    const int l15 = lane & 15;
    const int lk  = lane >> 4;       // 0..3
    const int mh  = wave >> 2;       // 0..1
    const int wn  = (wave & 3) * 16; // n-tile base

    f32x4 acc0 = (f32x4)0.0f, acc1 = (f32x4)0.0f;

    const int* qbase = qw + j0;
    const i32x4* wsa4 = (const i32x4*)g_wsa;

    // ---- pipeline registers ----
    i32x2 bvA[4], bvB[4], bvN[4];    // qweight: cur / +1 / +2
    i32x4 av0, av1;                  // A cells for next chunk to stage
    f32x2 sA, sB, sN;
    i32x2 zA, zB, zN;

    // prologue: B chunks 0,1; scales groups 0,1; A chunk 0
#pragma unroll
    for (int r = 0; r < 4; ++r) {
        bvA[r] = *(const i32x2*)(qbase + (size_t)(q * 4 + r) * N_DIM);
        bvB[r] = *(const i32x2*)(qbase + (size_t)(64 + q * 4 + r) * N_DIM);
    }
    sA = *(const f32x2*)(sc + j0);
    sB = *(const f32x2*)(sc + N_DIM + j0);
    zA = *(const i32x2*)(qz + j0);
    zB = *(const i32x2*)(qz + N_DIM + j0);
    av0 = wsa4[tid];
    av1 = wsa4[512 + tid];

    for (int c = 0; c < NCHUNK; ++c) {
        // ---- dequant current qweight quad (regs loaded 2 iters ago) ----
        // per-col constants: cz = -(1024+z) (exact f16), cs = s (f16)
        const __half2 cs0 = __half2half2(__float2half(sA.x));
        const __half2 cs1 = __half2half2(__float2half(sA.y));
        const __half2 cz0 = __half2half2(__float2half(-(1024.0f + (float)zA.x)));
        const __half2 cz1 = __half2half2(__float2half(-(1024.0f + (float)zA.y)));
        i32x4 c0, c1;
#pragma unroll
        for (int r = 0; r < 4; ++r) {
            c0[r] = (int)dq_word(bvA[r].x, cz0, cs0);
            c1[r] = (int)dq_word(bvA[r].y, cz1, cs1);
        }

        // barrier1: previous MFMA phase done reading LDS (no vmem drain)
        asm volatile("s_barrier" ::: "memory");

        // stage this chunk's tiles
        lB[q * 64 + 2 * p]          = __builtin_bit_cast(s16x8, c0);
        lB[q * 64 + 2 * p + 1]      = __builtin_bit_cast(s16x8, c1);
        lA[tid]       = __builtin_bit_cast(s16x8, av0);
        lA[512 + tid] = __builtin_bit_cast(s16x8, av1);

        // prefetch: A for c+1, B + scales for c+2 (wrapped; tail loads unused)
        const int ca = (c + 1) & (NCHUNK - 1);
        av0 = wsa4[(size_t)ca * 1024 + tid];
        av1 = wsa4[(size_t)ca * 1024 + 512 + tid];
        const int cb = (c + 2) & (NCHUNK - 1);
#pragma unroll
        for (int r = 0; r < 4; ++r)
            bvN[r] = *(const i32x2*)(qbase + (size_t)(cb * 64 + q * 4 + r) * N_DIM);
        sN = *(const f32x2*)(sc + (size_t)cb * N_DIM + j0);
        zN = *(const i32x2*)(qz + (size_t)cb * N_DIM + j0);

        // barrier2: LDS writes visible; vmem prefetches stay in flight
        asm volatile("s_waitcnt lgkmcnt(0)" ::: "memory");
        asm volatile("s_barrier" ::: "memory");
        __builtin_amdgcn_sched_barrier(0);

        // ---- MFMA (f16): wave does 2 m-tiles x 1 n-tile x 4 k-slices ----
#pragma unroll
        for (int ks = 0; ks < 4; ++ks) {
            const int cell = (ks * 4 + lk) * 64;
            const f16x8 bfr = __builtin_bit_cast(f16x8, lB[cell + wn + l15]);
            const f16x8 af0 = __builtin_bit_cast(f16x8, lA[cell + mh * 32 + l15]);
            const f16x8 af1 = __builtin_bit_cast(f16x8, lA[cell + mh * 32 + 16 + l15]);
            acc0 = __builtin_amdgcn_mfma_f32_16x16x32_f16(af0, bfr, acc0, 0, 0, 0);
            acc1 = __builtin_amdgcn_mfma_f32_16x16x32_f16(af1, bfr, acc1, 0, 0, 0);
        }

        // rotate pipeline
#pragma unroll
        for (int r = 0; r < 4; ++r) { bvA[r] = bvB[r]; bvB[r] = bvN[r]; }
        sA = sB; sB = sN; zA = zB; zB = zN;
    }

    // ---- epilogue: bias + store (verified C layout) ----
    const int   ncol = nbase + wn + l15;
    const float bv   = bias[ncol];
    const int   m0   = mh * 32 + lk * 4;
#pragma unroll
    for (int jj = 0; jj < 4; ++jj) {
        out[(size_t)(m0 + jj) * N_DIM + ncol]      = acc0[jj] + bv;
        out[(size_t)(m0 + 16 + jj) * N_DIM + ncol] = acc1[jj] + bv;
    }
}

extern "C" void kernel_launch(void* const* d_in, const int* in_sizes, int n_in,
                              void* d_out, int out_size, void* d_ws, size_t ws_size,
                              hipStream_t stream) {
    const float* x    = (const float*)d_in[0];
    const int*   qw   = (const int*)d_in[1];
    const float* sc   = (const float*)d_in[2];
    const int*   qz   = (const int*)d_in[3];
    const float* bias = (const float*)d_in[4];
    float*       out  = (float*)d_out;

    prep_a_kernel<<<dim3(256), dim3(256), 0, stream>>>(x);
    int4gemm_kernel<<<dim3(N_DIM / BN), dim3(512), 0, stream>>>(qw, sc, qz, bias, out);
}